// Round 3
// baseline (228.366 us; speedup 1.0000x reference)
//
#include <hip/hip_runtime.h>
#include <hip/hip_cooperative_groups.h>

namespace cg = cooperative_groups;

// Problem constants (fixed by the reference)
#define BATCH 32
#define NN    128                 // nodes
#define NIN   128                 // node features
#define NHID  256                 // hidden
#define NOUT  128                 // output features
#define ROWS  (BATCH * NN)        // 4096 flattened (b,n) rows

// Single cooperative kernel, grid = 512 blocks x 256 threads, 32 KB LDS.
//
// Phase 1 (block = 8 rows):  S = x@W1a ; R = x@W1b + b1        -> ws
// Phase 2 (block = (b, 32-recv tile, 64-ch chunk)):
//   G[b,n,c] = sum_{i != n} relu(S[b,i,c] + R[b,n,c])          -> ws
//   (thread = 4 float4-channels x 2 receivers; S-chunk staged in LDS,
//    read as ds_read_b128 with 4-way same-address broadcast = conflict-free)
// Phase 3 (block = 8 rows):  out = (G@W2 + 127*b2) / 127.000001
__global__ __launch_bounds__(256) void fused_all(
    const float* __restrict__ x,  const float* __restrict__ W1,
    const float* __restrict__ b1, const float* __restrict__ W2,
    const float* __restrict__ b2, float* __restrict__ S,
    float* __restrict__ R,        float* __restrict__ G,
    float* __restrict__ out)
{
    cg::grid_group grid = cg::this_grid();
    __shared__ float smem[128 * 64];      // 32 KB, re-purposed per phase
    const int t   = threadIdx.x;
    const int blk = blockIdx.x;

    // ------------------------- Phase 1: S, R -------------------------
    {
        float (*xr)[128] = (float (*)[128])smem;   // 8 x 128 = 4 KB
        const int row0 = blk * 8;
        for (int idx = t; idx < 8 * 128; idx += 256)
            xr[idx >> 7][idx & 127] = x[(size_t)row0 * NIN + idx];
        __syncthreads();

        const int c = t;                  // hidden channel 0..255
        float accs[8], accr[8];
#pragma unroll
        for (int r = 0; r < 8; ++r) { accs[r] = 0.f; accr[r] = 0.f; }

        for (int k = 0; k < NIN; k += 4) {
            float wa[4], wb[4];
#pragma unroll
            for (int kk = 0; kk < 4; ++kk) {
                wa[kk] = W1[(size_t)(k + kk) * NHID + c];        // sender half
                wb[kk] = W1[(size_t)(NIN + k + kk) * NHID + c];  // receiver half
            }
#pragma unroll
            for (int r = 0; r < 8; ++r) {
                const float4 xv = *(const float4*)(&xr[r][k]);   // uniform LDS broadcast
                accs[r] = fmaf(xv.w, wa[3], fmaf(xv.z, wa[2], fmaf(xv.y, wa[1], fmaf(xv.x, wa[0], accs[r]))));
                accr[r] = fmaf(xv.w, wb[3], fmaf(xv.z, wb[2], fmaf(xv.y, wb[1], fmaf(xv.x, wb[0], accr[r]))));
            }
        }
        const float bias = b1[c];
#pragma unroll
        for (int r = 0; r < 8; ++r) {
            S[(size_t)(row0 + r) * NHID + c] = accs[r];
            R[(size_t)(row0 + r) * NHID + c] = accr[r] + bias;
        }
    }
    grid.sync();

    // ------------------------- Phase 2: G -------------------------
    {
        // blk = b*16 + rt*4 + cc
        const int b  = blk >> 4;          // 0..31
        const int rt = (blk >> 2) & 3;    // receiver tile (32 each)
        const int cc = blk & 3;           // channel chunk (64 each)
        const int n0 = rt * 32;

        float4*       s4 = (float4*)smem;           // [128][16] float4 = 32 KB
        const float4* S4 = (const float4*)S;        // S row = 64 float4
        const float4* R4 = (const float4*)R;
        float4*       G4 = (float4*)G;

        for (int idx = t; idx < 2048; idx += 256)   // stage S[b, :, chunk]
            s4[idx] = S4[(size_t)(b * NN + (idx >> 4)) * 64 + cc * 16 + (idx & 15)];

        const int cg4 = t & 15;           // which float4 within the 64-ch chunk
        const int rq  = t >> 4;           // 0..15 -> receivers n0+rq*2, +1
        const int nA  = n0 + rq * 2;
        const int nB  = nA + 1;
        const float4 rvA = R4[(size_t)(b * NN + nA) * 64 + cc * 16 + cg4];
        const float4 rvB = R4[(size_t)(b * NN + nB) * 64 + cc * 16 + cg4];
        __syncthreads();

        float4 aA = {0.f, 0.f, 0.f, 0.f}, aB = {0.f, 0.f, 0.f, 0.f};
        for (int i = 0; i < 128; ++i) {
            const float4 s = s4[i * 16 + cg4];      // b128, 4-way broadcast: free
            aA.x += fmaxf(s.x + rvA.x, 0.f);  aB.x += fmaxf(s.x + rvB.x, 0.f);
            aA.y += fmaxf(s.y + rvA.y, 0.f);  aB.y += fmaxf(s.y + rvB.y, 0.f);
            aA.z += fmaxf(s.z + rvA.z, 0.f);  aB.z += fmaxf(s.z + rvB.z, 0.f);
            aA.w += fmaxf(s.w + rvA.w, 0.f);  aB.w += fmaxf(s.w + rvB.w, 0.f);
        }
        // remove self-edges
        const float4 sA = s4[nA * 16 + cg4];
        const float4 sB = s4[nB * 16 + cg4];
        aA.x -= fmaxf(sA.x + rvA.x, 0.f);  aB.x -= fmaxf(sB.x + rvB.x, 0.f);
        aA.y -= fmaxf(sA.y + rvA.y, 0.f);  aB.y -= fmaxf(sB.y + rvB.y, 0.f);
        aA.z -= fmaxf(sA.z + rvA.z, 0.f);  aB.z -= fmaxf(sB.z + rvB.z, 0.f);
        aA.w -= fmaxf(sA.w + rvA.w, 0.f);  aB.w -= fmaxf(sB.w + rvB.w, 0.f);

        G4[(size_t)(b * NN + nA) * 64 + cc * 16 + cg4] = aA;
        G4[(size_t)(b * NN + nB) * 64 + cc * 16 + cg4] = aB;
    }
    grid.sync();

    // ------------------------- Phase 3: out = G@W2 -------------------------
    {
        float (*g)[256] = (float (*)[256])smem;     // 8 x 256 = 8 KB
        const int row0 = blk * 8;
        const float4* G4 = (const float4*)G;
        float4* g4 = (float4*)smem;
        for (int idx = t; idx < 512; idx += 256)    // stage 8 G rows
            g4[idx] = G4[(size_t)row0 * 64 + idx];
        __syncthreads();

        const int c  = t & 127;           // output channel
        const int rh = t >> 7;            // row half: 4 rows each
        float acc[4] = {0.f, 0.f, 0.f, 0.f};

        for (int k = 0; k < NHID; k += 4) {
            float w[4];
#pragma unroll
            for (int kk = 0; kk < 4; ++kk)
                w[kk] = W2[(size_t)(k + kk) * NOUT + c];
#pragma unroll
            for (int r = 0; r < 4; ++r) {
                const float4 gv = *(const float4*)(&g[rh * 4 + r][k]);  // uniform broadcast
                acc[r] = fmaf(gv.w, w[3], fmaf(gv.z, w[2], fmaf(gv.y, w[1], fmaf(gv.x, w[0], acc[r]))));
            }
        }
        const float inv  = 1.0f / (127.0f + 1e-6f);
        const float bias = 127.0f * b2[c];
#pragma unroll
        for (int r = 0; r < 4; ++r)
            out[(size_t)(row0 + rh * 4 + r) * NOUT + c] = (acc[r] + bias) * inv;
    }
}

// ---------------------------------------------------------------------------
extern "C" void kernel_launch(void* const* d_in, const int* in_sizes, int n_in,
                              void* d_out, int out_size, void* d_ws, size_t ws_size,
                              hipStream_t stream)
{
    const float* x  = (const float*)d_in[0];
    // d_in[1] rel_type, d_in[2] rel_rec, d_in[3] rel_send: structurally fixed, unused
    const float* W1 = (const float*)d_in[4];
    const float* b1 = (const float*)d_in[5];
    const float* W2 = (const float*)d_in[6];
    const float* b2 = (const float*)d_in[7];
    float* out = (float*)d_out;

    float* S = (float*)d_ws;                       // 4 MB
    float* R = S + (size_t)ROWS * NHID;            // 4 MB
    float* G = R + (size_t)ROWS * NHID;            // 4 MB (12 MB total of ws)

    void* args[] = { (void*)&x, (void*)&W1, (void*)&b1, (void*)&W2, (void*)&b2,
                     (void*)&S, (void*)&R, (void*)&G, (void*)&out };
    hipLaunchCooperativeKernel((void*)fused_all, dim3(512), dim3(256), args, 0, stream);
}

// Round 4
// 176.259 us; speedup vs baseline: 1.2956x; 1.2956x over previous
//
#include <hip/hip_runtime.h>

// Problem constants (fixed by the reference)
#define BATCH 32
#define NN    128                 // nodes
#define NIN   128                 // node features
#define NHID  256                 // hidden
#define NOUT  128                 // output features
#define ROWS  (BATCH * NN)        // 4096 flattened (b,n) rows

__device__ __forceinline__ float4 fma4(float a, const float4 w, const float4 c) {
    float4 r;
    r.x = fmaf(a, w.x, c.x); r.y = fmaf(a, w.y, c.y);
    r.z = fmaf(a, w.z, c.z); r.w = fmaf(a, w.w, c.w);
    return r;
}

// ---------------------------------------------------------------------------
// K1: S[row,c] = x[row,:] @ W1[0:128, c] ;  R[row,c] = x[row,:] @ W1[128:,c] + b1
// 16 rows/block (256 blocks), thread = 4 channels (float4) x 4 rows.
// W1 loads are dwordx4 (1 KB/wave-inst); x rows read from LDS as b128.
// ---------------------------------------------------------------------------
__global__ __launch_bounds__(256) void k1_sr(
    const float* __restrict__ x, const float* __restrict__ W1,
    const float* __restrict__ b1, float* __restrict__ S, float* __restrict__ R)
{
    __shared__ float xr[16][128];         // 8 KB
    const int row0 = blockIdx.x * 16;
    const int t = threadIdx.x;
    const float4* x4 = (const float4*)(x + (size_t)row0 * NIN);
    float4* xr4 = (float4*)xr;
    for (int idx = t; idx < 512; idx += 256) xr4[idx] = x4[idx];
    __syncthreads();

    const int c4 = (t & 63) * 4;          // 4 consecutive hidden channels
    const int r0 = (t >> 6) * 4;          // 4 rows
    float4 accs[4], accr[4];
#pragma unroll
    for (int r = 0; r < 4; ++r) {
        accs[r] = make_float4(0.f, 0.f, 0.f, 0.f);
        accr[r] = make_float4(0.f, 0.f, 0.f, 0.f);
    }

    for (int k = 0; k < NIN; k += 4) {
        float4 wa[4], wb[4];
#pragma unroll
        for (int kk = 0; kk < 4; ++kk) {
            wa[kk] = *(const float4*)&W1[(size_t)(k + kk) * NHID + c4];
            wb[kk] = *(const float4*)&W1[(size_t)(NIN + k + kk) * NHID + c4];
        }
#pragma unroll
        for (int r = 0; r < 4; ++r) {
            const float4 xv = *(const float4*)(&xr[r0 + r][k]);   // b128 broadcast
            accs[r] = fma4(xv.x, wa[0], fma4(xv.y, wa[1], fma4(xv.z, wa[2], fma4(xv.w, wa[3], accs[r]))));
            accr[r] = fma4(xv.x, wb[0], fma4(xv.y, wb[1], fma4(xv.z, wb[2], fma4(xv.w, wb[3], accr[r]))));
        }
    }
    const float4 bias = *(const float4*)&b1[c4];
#pragma unroll
    for (int r = 0; r < 4; ++r) {
        *(float4*)&S[(size_t)(row0 + r0 + r) * NHID + c4] = accs[r];
        float4 rr = accr[r];
        rr.x += bias.x; rr.y += bias.y; rr.z += bias.z; rr.w += bias.w;
        *(float4*)&R[(size_t)(row0 + r0 + r) * NHID + c4] = rr;
    }
}

// ---------------------------------------------------------------------------
// K2: G[b,n,c] = sum_{i != n} relu(S[b,i,c] + R[b,n,c])
// Block = (b, 64-ch chunk, 64-recv half): 32*4*2 = 256 blocks.
// Thread = 1 float4 of channels x 4 receivers; S-chunk (32 KB) in LDS,
// read as ds_read_b128 4-lane broadcast (2-way bank alias = free).
// ---------------------------------------------------------------------------
__global__ __launch_bounds__(256) void k2_g(
    const float* __restrict__ S, const float* __restrict__ R, float* __restrict__ G)
{
    const int blk = blockIdx.x;
    const int b   = blk >> 3;             // 0..31
    const int cc  = (blk >> 1) & 3;       // channel chunk (64 each)
    const int rh  = blk & 1;              // receiver half (64 each)

    __shared__ float4 s4[128 * 16];       // 32 KB: S[b, all senders, chunk]
    const float4* S4 = (const float4*)S;  // S row = 64 float4
    const float4* R4 = (const float4*)R;
    float4*       G4 = (float4*)G;
    const int t = threadIdx.x;

    for (int idx = t; idx < 2048; idx += 256)
        s4[idx] = S4[(size_t)(b * NN + (idx >> 4)) * 64 + cc * 16 + (idx & 15)];

    const int cg = t & 15;                // which float4 within the chunk
    const int n0 = rh * 64 + (t >> 4) * 4;
    float4 rv[4], acc[4];
#pragma unroll
    for (int q = 0; q < 4; ++q) {
        rv[q]  = R4[(size_t)(b * NN + n0 + q) * 64 + cc * 16 + cg];
        acc[q] = make_float4(0.f, 0.f, 0.f, 0.f);
    }
    __syncthreads();

    for (int i = 0; i < 128; ++i) {
        const float4 s = s4[i * 16 + cg];
#pragma unroll
        for (int q = 0; q < 4; ++q) {
            acc[q].x += fmaxf(s.x + rv[q].x, 0.f);
            acc[q].y += fmaxf(s.y + rv[q].y, 0.f);
            acc[q].z += fmaxf(s.z + rv[q].z, 0.f);
            acc[q].w += fmaxf(s.w + rv[q].w, 0.f);
        }
    }
#pragma unroll
    for (int q = 0; q < 4; ++q) {         // remove self-edge
        const float4 sq = s4[(n0 + q) * 16 + cg];
        acc[q].x -= fmaxf(sq.x + rv[q].x, 0.f);
        acc[q].y -= fmaxf(sq.y + rv[q].y, 0.f);
        acc[q].z -= fmaxf(sq.z + rv[q].z, 0.f);
        acc[q].w -= fmaxf(sq.w + rv[q].w, 0.f);
        G4[(size_t)(b * NN + n0 + q) * 64 + cc * 16 + cg] = acc[q];
    }
}

// ---------------------------------------------------------------------------
// K3: out[row,c] = (G[row,:] @ W2[:,c] + 127*b2[c]) / 127.000001
// 16 rows/block (256 blocks), thread = 4 channels (float4) x 2 rows.
// ---------------------------------------------------------------------------
__global__ __launch_bounds__(256) void k3_out(
    const float* __restrict__ G, const float* __restrict__ W2,
    const float* __restrict__ b2, float* __restrict__ out)
{
    __shared__ float g[16][256];          // 16 KB
    const int row0 = blockIdx.x * 16;
    const int t = threadIdx.x;
    const float4* Gg = (const float4*)(G + (size_t)row0 * NHID);
    float4* g4 = (float4*)g;
    for (int idx = t; idx < 1024; idx += 256) g4[idx] = Gg[idx];
    __syncthreads();

    const int c4 = (t & 31) * 4;          // 4 consecutive output channels
    const int r0 = (t >> 5) * 2;          // 2 rows
    float4 acc[2];
    acc[0] = make_float4(0.f, 0.f, 0.f, 0.f);
    acc[1] = make_float4(0.f, 0.f, 0.f, 0.f);

    for (int k = 0; k < NHID; k += 4) {
        float4 w[4];
#pragma unroll
        for (int kk = 0; kk < 4; ++kk)
            w[kk] = *(const float4*)&W2[(size_t)(k + kk) * NOUT + c4];
#pragma unroll
        for (int r = 0; r < 2; ++r) {
            const float4 gv = *(const float4*)(&g[r0 + r][k]);    // b128 broadcast
            acc[r] = fma4(gv.x, w[0], fma4(gv.y, w[1], fma4(gv.z, w[2], fma4(gv.w, w[3], acc[r]))));
        }
    }
    const float inv = 1.0f / (127.0f + 1e-6f);
    float4 bias = *(const float4*)&b2[c4];
    bias.x *= 127.f; bias.y *= 127.f; bias.z *= 127.f; bias.w *= 127.f;
#pragma unroll
    for (int r = 0; r < 2; ++r) {
        float4 o;
        o.x = (acc[r].x + bias.x) * inv;
        o.y = (acc[r].y + bias.y) * inv;
        o.z = (acc[r].z + bias.z) * inv;
        o.w = (acc[r].w + bias.w) * inv;
        *(float4*)&out[(size_t)(row0 + r0 + r) * NOUT + c4] = o;
    }
}

// ---------------------------------------------------------------------------
extern "C" void kernel_launch(void* const* d_in, const int* in_sizes, int n_in,
                              void* d_out, int out_size, void* d_ws, size_t ws_size,
                              hipStream_t stream)
{
    const float* x  = (const float*)d_in[0];
    // d_in[1] rel_type, d_in[2] rel_rec, d_in[3] rel_send: structurally fixed, unused
    const float* W1 = (const float*)d_in[4];
    const float* b1 = (const float*)d_in[5];
    const float* W2 = (const float*)d_in[6];
    const float* b2 = (const float*)d_in[7];
    float* out = (float*)d_out;

    float* S = (float*)d_ws;                       // 4 MB
    float* R = S + (size_t)ROWS * NHID;            // 4 MB
    float* G = R + (size_t)ROWS * NHID;            // 4 MB (12 MB total of ws)

    k1_sr <<<ROWS / 16, 256, 0, stream>>>(x, W1, b1, S, R);
    k2_g  <<<256,       256, 0, stream>>>(S, R, G);
    k3_out<<<ROWS / 16, 256, 0, stream>>>(G, W2, b2, out);
}

// Round 5
// 135.380 us; speedup vs baseline: 1.6868x; 1.3020x over previous
//
#include <hip/hip_runtime.h>

// Problem constants (fixed by the reference)
#define BATCH 32
#define NN    128                 // nodes
#define NIN   128                 // node features
#define NHID  256                 // hidden
#define NOUT  128                 // output features
#define ROWS  (BATCH * NN)        // 4096 flattened (b,n) rows

__device__ __forceinline__ float4 fma4(float a, const float4 w, const float4 c) {
    float4 r;
    r.x = fmaf(a, w.x, c.x); r.y = fmaf(a, w.y, c.y);
    r.z = fmaf(a, w.z, c.z); r.w = fmaf(a, w.w, c.w);
    return r;
}

// ---------------------------------------------------------------------------
// K1: S[row,c] = x[row,:] @ W1[0:128, c] ;  R[row,c] = x[row,:] @ W1[128:,c] + b1
// Channel-per-lane layout: thread = 1 hidden channel x 8 rows.
// Grid 512 x 256 (2 blocks/CU, 8 waves/CU). No LDS, no syncthreads.
//  - x loads: uniform address (no threadIdx in index) -> one 16B broadcast
//    fetch per wave, L1-resident (4 KB/block).
//  - W1 loads: lane c consecutive -> 256B coalesced dword, 8 independent per
//    k-chunk (vmcnt-batchable). W reuse = 8 rows/wave -> 128 MB L2 total.
//  - acc = 16 scalar VGPRs; total ~70 VGPRs, no spill risk.
// ---------------------------------------------------------------------------
__global__ __launch_bounds__(256, 4) void k1_sr(
    const float* __restrict__ x, const float* __restrict__ W1,
    const float* __restrict__ b1, float* __restrict__ S, float* __restrict__ R)
{
    const int t    = threadIdx.x;
    const int c    = (t >> 6) * 64 + (t & 63);   // this thread's hidden channel
    const int row0 = blockIdx.x * 8;

    float accs[8], accr[8];
#pragma unroll
    for (int r = 0; r < 8; ++r) { accs[r] = 0.f; accr[r] = 0.f; }

    for (int k = 0; k < NIN; k += 4) {
        float wa[4], wb[4];
#pragma unroll
        for (int kk = 0; kk < 4; ++kk) {
            wa[kk] = W1[(size_t)(k + kk) * NHID + c];          // sender half
            wb[kk] = W1[(size_t)(NIN + k + kk) * NHID + c];    // receiver half
        }
#pragma unroll
        for (int r = 0; r < 8; ++r) {
            // uniform address -> wave-wide broadcast load (L1-hit after first use)
            const float4 xv = *(const float4*)&x[(size_t)(row0 + r) * NIN + k];
            accs[r] = fmaf(xv.x, wa[0], fmaf(xv.y, wa[1], fmaf(xv.z, wa[2], fmaf(xv.w, wa[3], accs[r]))));
            accr[r] = fmaf(xv.x, wb[0], fmaf(xv.y, wb[1], fmaf(xv.z, wb[2], fmaf(xv.w, wb[3], accr[r]))));
        }
    }
    const float bias = b1[c];
#pragma unroll
    for (int r = 0; r < 8; ++r) {
        S[(size_t)(row0 + r) * NHID + c] = accs[r];
        R[(size_t)(row0 + r) * NHID + c] = accr[r] + bias;
    }
}

// ---------------------------------------------------------------------------
// K2: G[b,n,c] = sum_{i != n} relu(S[b,i,c] + R[b,n,c])     (unchanged)
// Block = (b, 64-ch chunk, 64-recv half): 256 blocks.
// Thread = 1 float4 of channels x 4 receivers; S-chunk (32 KB) in LDS.
// ---------------------------------------------------------------------------
__global__ __launch_bounds__(256) void k2_g(
    const float* __restrict__ S, const float* __restrict__ R, float* __restrict__ G)
{
    const int blk = blockIdx.x;
    const int b   = blk >> 3;             // 0..31
    const int cc  = (blk >> 1) & 3;       // channel chunk (64 each)
    const int rh  = blk & 1;              // receiver half (64 each)

    __shared__ float4 s4[128 * 16];       // 32 KB: S[b, all senders, chunk]
    const float4* S4 = (const float4*)S;  // S row = 64 float4
    const float4* R4 = (const float4*)R;
    float4*       G4 = (float4*)G;
    const int t = threadIdx.x;

    for (int idx = t; idx < 2048; idx += 256)
        s4[idx] = S4[(size_t)(b * NN + (idx >> 4)) * 64 + cc * 16 + (idx & 15)];

    const int cg = t & 15;                // which float4 within the chunk
    const int n0 = rh * 64 + (t >> 4) * 4;
    float4 rv[4], acc[4];
#pragma unroll
    for (int q = 0; q < 4; ++q) {
        rv[q]  = R4[(size_t)(b * NN + n0 + q) * 64 + cc * 16 + cg];
        acc[q] = make_float4(0.f, 0.f, 0.f, 0.f);
    }
    __syncthreads();

    for (int i = 0; i < 128; ++i) {
        const float4 s = s4[i * 16 + cg]; // b128, 4-lane broadcast, conflict-free
#pragma unroll
        for (int q = 0; q < 4; ++q) {
            acc[q].x += fmaxf(s.x + rv[q].x, 0.f);
            acc[q].y += fmaxf(s.y + rv[q].y, 0.f);
            acc[q].z += fmaxf(s.z + rv[q].z, 0.f);
            acc[q].w += fmaxf(s.w + rv[q].w, 0.f);
        }
    }
#pragma unroll
    for (int q = 0; q < 4; ++q) {         // remove self-edge
        const float4 sq = s4[(n0 + q) * 16 + cg];
        acc[q].x -= fmaxf(sq.x + rv[q].x, 0.f);
        acc[q].y -= fmaxf(sq.y + rv[q].y, 0.f);
        acc[q].z -= fmaxf(sq.z + rv[q].z, 0.f);
        acc[q].w -= fmaxf(sq.w + rv[q].w, 0.f);
        G4[(size_t)(b * NN + n0 + q) * 64 + cc * 16 + cg] = acc[q];
    }
}

// ---------------------------------------------------------------------------
// K3: out[row,c] = (G[row,:] @ W2[:,c] + 127*b2[c]) / 127.000001   (unchanged)
// 16 rows/block (256 blocks), thread = 4 channels (float4) x 2 rows.
// ---------------------------------------------------------------------------
__global__ __launch_bounds__(256) void k3_out(
    const float* __restrict__ G, const float* __restrict__ W2,
    const float* __restrict__ b2, float* __restrict__ out)
{
    __shared__ float g[16][256];          // 16 KB
    const int row0 = blockIdx.x * 16;
    const int t = threadIdx.x;
    const float4* Gg = (const float4*)(G + (size_t)row0 * NHID);
    float4* g4 = (float4*)g;
    for (int idx = t; idx < 1024; idx += 256) g4[idx] = Gg[idx];
    __syncthreads();

    const int c4 = (t & 31) * 4;          // 4 consecutive output channels
    const int r0 = (t >> 5) * 2;          // 2 rows
    float4 acc[2];
    acc[0] = make_float4(0.f, 0.f, 0.f, 0.f);
    acc[1] = make_float4(0.f, 0.f, 0.f, 0.f);

    for (int k = 0; k < NHID; k += 4) {
        float4 w[4];
#pragma unroll
        for (int kk = 0; kk < 4; ++kk)
            w[kk] = *(const float4*)&W2[(size_t)(k + kk) * NOUT + c4];
#pragma unroll
        for (int r = 0; r < 2; ++r) {
            const float4 gv = *(const float4*)(&g[r0 + r][k]);    // b128 broadcast
            acc[r] = fma4(gv.x, w[0], fma4(gv.y, w[1], fma4(gv.z, w[2], fma4(gv.w, w[3], acc[r]))));
        }
    }
    const float inv = 1.0f / (127.0f + 1e-6f);
    float4 bias = *(const float4*)&b2[c4];
    bias.x *= 127.f; bias.y *= 127.f; bias.z *= 127.f; bias.w *= 127.f;
#pragma unroll
    for (int r = 0; r < 2; ++r) {
        float4 o;
        o.x = (acc[r].x + bias.x) * inv;
        o.y = (acc[r].y + bias.y) * inv;
        o.z = (acc[r].z + bias.z) * inv;
        o.w = (acc[r].w + bias.w) * inv;
        *(float4*)&out[(size_t)(row0 + r0 + r) * NOUT + c4] = o;
    }
}

// ---------------------------------------------------------------------------
extern "C" void kernel_launch(void* const* d_in, const int* in_sizes, int n_in,
                              void* d_out, int out_size, void* d_ws, size_t ws_size,
                              hipStream_t stream)
{
    const float* x  = (const float*)d_in[0];
    // d_in[1] rel_type, d_in[2] rel_rec, d_in[3] rel_send: structurally fixed, unused
    const float* W1 = (const float*)d_in[4];
    const float* b1 = (const float*)d_in[5];
    const float* W2 = (const float*)d_in[6];
    const float* b2 = (const float*)d_in[7];
    float* out = (float*)d_out;

    float* S = (float*)d_ws;                       // 4 MB
    float* R = S + (size_t)ROWS * NHID;            // 4 MB
    float* G = R + (size_t)ROWS * NHID;            // 4 MB (12 MB total of ws)

    k1_sr <<<ROWS / 8,  256, 0, stream>>>(x, W1, b1, S, R);
    k2_g  <<<256,       256, 0, stream>>>(S, R, G);
    k3_out<<<ROWS / 16, 256, 0, stream>>>(G, W2, b2, out);
}

// Round 6
// 128.479 us; speedup vs baseline: 1.7775x; 1.0537x over previous
//
#include <hip/hip_runtime.h>

// Problem constants (fixed by the reference)
#define BATCH 32
#define NN    128                 // nodes
#define NIN   128                 // node features
#define NHID  256                 // hidden
#define NOUT  128                 // output features
#define ROWS  (BATCH * NN)        // 4096 flattened (b,n) rows

__device__ __forceinline__ float4 fma4(float a, const float4 w, const float4 c) {
    float4 r;
    r.x = fmaf(a, w.x, c.x); r.y = fmaf(a, w.y, c.y);
    r.z = fmaf(a, w.z, c.z); r.w = fmaf(a, w.w, c.w);
    return r;
}
#define XK(v, kk) ((kk) == 0 ? (v).x : (kk) == 1 ? (v).y : (kk) == 2 ? (v).z : (v).w)

// ---------------------------------------------------------------------------
// K1 as LDS-resident GEMM: [4096 x 128] @ [128 x 512]  (512 cols = S || R).
// Lesson from R4/R5: global loads inside the k-loop latency-serialize at low
// occupancy; k2's stage-once-then-LDS-only pattern runs at model speed. So:
// block = 64 rows x 64 cols; LDS = x-tile 32 KB + W-tile 32 KB = 64 KB.
// Grid 512 (64 row-tiles x 8 col-tiles) = 2 blocks/CU, 8 waves/CU.
// Thread = 4 rows (stride 16) x 4 cols (float4). Inner loop: LDS only.
// x-tile XOR-swizzled (f4idx ^= row&7) so per-inst 4-distinct-row broadcast
// reads spread across banks (2-way = free). W reads: 16 consecutive float4
// x 4-lane broadcast = free.
// ---------------------------------------------------------------------------
__global__ __launch_bounds__(256, 2) void k1_gemm(
    const float* __restrict__ x, const float* __restrict__ W1,
    const float* __restrict__ b1, float* __restrict__ S, float* __restrict__ R)
{
    __shared__ float4 xl[64 * 32];        // x-tile: 64 rows x 128 k (swizzled), 32 KB
    __shared__ float4 wl[128 * 16];       // W-tile: 128 k x 64 cols, 32 KB

    const int t  = threadIdx.x;
    const int ct = blockIdx.x & 7;        // col-tile: h = ct>>2 (S/R half), c0 = (ct&3)*64
    const int rt = blockIdx.x >> 3;       // row-tile (64 rows)
    const int h  = ct >> 2;
    const int c0 = (ct & 3) * 64;
    const int row0 = rt * 64;

    // stage x rows row0..row0+63 (contiguous 32 KB), swizzled f4-index
    {
        const float4* Xg = (const float4*)(x + (size_t)row0 * NIN);
        for (int idx = t; idx < 2048; idx += 256) {
            const int row = idx >> 5, jj = idx & 31;
            xl[row * 32 + (jj ^ (row & 7))] = Xg[idx];
        }
    }
    // stage W1[h*128 .. h*128+127][c0 .. c0+63]
    {
        const float4* Wg = (const float4*)W1;
        for (int idx = t; idx < 2048; idx += 256) {
            const int row = idx >> 4, jj = idx & 15;
            wl[idx] = Wg[(size_t)(h * 128 + row) * 64 + (c0 >> 2) + jj];
        }
    }
    __syncthreads();

    const int cl = t & 15;                // this thread's float4 of cols
    const int rg = t >> 4;                // base row 0..15; rows rg, rg+16, rg+32, rg+48
    const int sw = rg & 7;                // x swizzle for all 4 rows (16j keeps row&7)

    float4 acc[4];
#pragma unroll
    for (int j = 0; j < 4; ++j) acc[j] = make_float4(0.f, 0.f, 0.f, 0.f);

    for (int k = 0; k < 128; k += 4) {
        const int kx = (k >> 2) ^ sw;
        float4 xv[4];
#pragma unroll
        for (int j = 0; j < 4; ++j)
            xv[j] = xl[(rg + 16 * j) * 32 + kx];      // 4-distinct-addr broadcast, swizzle-spread
#pragma unroll
        for (int kk = 0; kk < 4; ++kk) {
            const float4 w = wl[(k + kk) * 16 + cl];  // 16 consecutive f4 x 4-way bcast: free
#pragma unroll
            for (int j = 0; j < 4; ++j)
                acc[j] = fma4(XK(xv[j], kk), w, acc[j]);
        }
    }

    float* dst = h ? R : S;
    float4 bias = make_float4(0.f, 0.f, 0.f, 0.f);
    if (h) bias = *(const float4*)&b1[c0 + cl * 4];
#pragma unroll
    for (int j = 0; j < 4; ++j) {
        float4 v = acc[j];
        v.x += bias.x; v.y += bias.y; v.z += bias.z; v.w += bias.w;
        *(float4*)&dst[(size_t)(row0 + rg + 16 * j) * NHID + c0 + cl * 4] = v;
    }
}

// ---------------------------------------------------------------------------
// K2: G[b,n,c] = sum_{i != n} relu(S[b,i,c] + R[b,n,c])     (unchanged)
// Block = (b, 64-ch chunk, 64-recv half): 256 blocks.
// Thread = 1 float4 of channels x 4 receivers; S-chunk (32 KB) in LDS.
// ---------------------------------------------------------------------------
__global__ __launch_bounds__(256) void k2_g(
    const float* __restrict__ S, const float* __restrict__ R, float* __restrict__ G)
{
    const int blk = blockIdx.x;
    const int b   = blk >> 3;             // 0..31
    const int cc  = (blk >> 1) & 3;       // channel chunk (64 each)
    const int rh  = blk & 1;              // receiver half (64 each)

    __shared__ float4 s4[128 * 16];       // 32 KB: S[b, all senders, chunk]
    const float4* S4 = (const float4*)S;  // S row = 64 float4
    const float4* R4 = (const float4*)R;
    float4*       G4 = (float4*)G;
    const int t = threadIdx.x;

    for (int idx = t; idx < 2048; idx += 256)
        s4[idx] = S4[(size_t)(b * NN + (idx >> 4)) * 64 + cc * 16 + (idx & 15)];

    const int cg = t & 15;                // which float4 within the chunk
    const int n0 = rh * 64 + (t >> 4) * 4;
    float4 rv[4], acc[4];
#pragma unroll
    for (int q = 0; q < 4; ++q) {
        rv[q]  = R4[(size_t)(b * NN + n0 + q) * 64 + cc * 16 + cg];
        acc[q] = make_float4(0.f, 0.f, 0.f, 0.f);
    }
    __syncthreads();

    for (int i = 0; i < 128; ++i) {
        const float4 s = s4[i * 16 + cg]; // b128, 4-lane broadcast, conflict-free
#pragma unroll
        for (int q = 0; q < 4; ++q) {
            acc[q].x += fmaxf(s.x + rv[q].x, 0.f);
            acc[q].y += fmaxf(s.y + rv[q].y, 0.f);
            acc[q].z += fmaxf(s.z + rv[q].z, 0.f);
            acc[q].w += fmaxf(s.w + rv[q].w, 0.f);
        }
    }
#pragma unroll
    for (int q = 0; q < 4; ++q) {         // remove self-edge
        const float4 sq = s4[(n0 + q) * 16 + cg];
        acc[q].x -= fmaxf(sq.x + rv[q].x, 0.f);
        acc[q].y -= fmaxf(sq.y + rv[q].y, 0.f);
        acc[q].z -= fmaxf(sq.z + rv[q].z, 0.f);
        acc[q].w -= fmaxf(sq.w + rv[q].w, 0.f);
        G4[(size_t)(b * NN + n0 + q) * 64 + cc * 16 + cg] = acc[q];
    }
}

// ---------------------------------------------------------------------------
// K3: out[row,c] = (G[row,:] @ W2[:,c] + 127*b2[c]) / 127.000001   (unchanged)
// 16 rows/block (256 blocks), thread = 4 channels (float4) x 2 rows.
// ---------------------------------------------------------------------------
__global__ __launch_bounds__(256) void k3_out(
    const float* __restrict__ G, const float* __restrict__ W2,
    const float* __restrict__ b2, float* __restrict__ out)
{
    __shared__ float g[16][256];          // 16 KB
    const int row0 = blockIdx.x * 16;
    const int t = threadIdx.x;
    const float4* Gg = (const float4*)(G + (size_t)row0 * NHID);
    float4* g4 = (float4*)g;
    for (int idx = t; idx < 1024; idx += 256) g4[idx] = Gg[idx];
    __syncthreads();

    const int c4 = (t & 31) * 4;          // 4 consecutive output channels
    const int r0 = (t >> 5) * 2;          // 2 rows
    float4 acc[2];
    acc[0] = make_float4(0.f, 0.f, 0.f, 0.f);
    acc[1] = make_float4(0.f, 0.f, 0.f, 0.f);

    for (int k = 0; k < NHID; k += 4) {
        float4 w[4];
#pragma unroll
        for (int kk = 0; kk < 4; ++kk)
            w[kk] = *(const float4*)&W2[(size_t)(k + kk) * NOUT + c4];
#pragma unroll
        for (int r = 0; r < 2; ++r) {
            const float4 gv = *(const float4*)(&g[r0 + r][k]);    // b128 broadcast
            acc[r] = fma4(gv.x, w[0], fma4(gv.y, w[1], fma4(gv.z, w[2], fma4(gv.w, w[3], acc[r]))));
        }
    }
    const float inv = 1.0f / (127.0f + 1e-6f);
    float4 bias = *(const float4*)&b2[c4];
    bias.x *= 127.f; bias.y *= 127.f; bias.z *= 127.f; bias.w *= 127.f;
#pragma unroll
    for (int r = 0; r < 2; ++r) {
        float4 o;
        o.x = (acc[r].x + bias.x) * inv;
        o.y = (acc[r].y + bias.y) * inv;
        o.z = (acc[r].z + bias.z) * inv;
        o.w = (acc[r].w + bias.w) * inv;
        *(float4*)&out[(size_t)(row0 + r0 + r) * NOUT + c4] = o;
    }
}

// ---------------------------------------------------------------------------
extern "C" void kernel_launch(void* const* d_in, const int* in_sizes, int n_in,
                              void* d_out, int out_size, void* d_ws, size_t ws_size,
                              hipStream_t stream)
{
    const float* x  = (const float*)d_in[0];
    // d_in[1] rel_type, d_in[2] rel_rec, d_in[3] rel_send: structurally fixed, unused
    const float* W1 = (const float*)d_in[4];
    const float* b1 = (const float*)d_in[5];
    const float* W2 = (const float*)d_in[6];
    const float* b2 = (const float*)d_in[7];
    float* out = (float*)d_out;

    float* S = (float*)d_ws;                       // 4 MB
    float* R = S + (size_t)ROWS * NHID;            // 4 MB
    float* G = R + (size_t)ROWS * NHID;            // 4 MB (12 MB total of ws)

    k1_gemm<<<512,       256, 0, stream>>>(x, W1, b1, S, R);
    k2_g   <<<256,       256, 0, stream>>>(S, R, G);
    k3_out <<<ROWS / 16, 256, 0, stream>>>(G, W2, b2, out);
}